// Round 6
// baseline (256.655 us; speedup 1.0000x reference)
//
#include <hip/hip_runtime.h>
#include <hip/hip_bf16.h>
#include <math.h>

// ---------------------------------------------------------------------------
// GATConv forward.  N=100000, E=1.6M, IN=128, OUT*HEADS=128 (OUT=32, H=4).
// Round 6:
//   - gemm_deg: grid-fused {MFMA bf16x3 gemm (head-major bf16 Z)} || {deg_cnt
//     with rank capture} -- independent chains overlap, one launch gap saved.
//   - node_scan: grid-fused {node_e from head-major Zh} || {scan1}.
//   - scan2 -> fill (scan3 folded via bsum[r>>8]) as before.
//   - gather: two-phase wave processing.  Phase A: 64 lanes = 16 edges x 4
//     heads compute exp ONCE per (edge,head) + accumulate denom; phase B:
//     ds_bpermute broadcasts (xv, col) in-register, each lane does 1 dword
//     Zh load + 2 fma.  Kills the 16x redundant exp of round 5.
// ---------------------------------------------------------------------------

typedef __attribute__((ext_vector_type(8))) short bf16x8;
typedef __attribute__((ext_vector_type(4))) float f32x4;

__device__ __forceinline__ ushort f2bf(float f) {
  __hip_bfloat16 h = __float2bfloat16(f);   // RNE
  return __builtin_bit_cast(ushort, h);
}
__device__ __forceinline__ float bf2f(ushort u) {
  unsigned v = ((unsigned)u) << 16;
  return __builtin_bit_cast(float, v);
}

// ---- fused: gemm blocks [0, G1) | deg_cnt blocks [G1, G1+G2) ----
__global__ __launch_bounds__(256, 2) void gemm_deg(
    const float* __restrict__ x, const float* __restrict__ W,
    const float* __restrict__ bias, ushort* __restrict__ Zh, int N,
    const int* __restrict__ row, int* __restrict__ deg,
    int* __restrict__ rank, int E, int G1) {
  __shared__ ushort xh[64 * 128];
  __shared__ ushort xl[64 * 128];

  if ((int)blockIdx.x >= G1) {
    int e = ((int)blockIdx.x - G1) * 256 + threadIdx.x;
    if (e < E) rank[e] = atomicAdd(&deg[row[e]], 1);
    return;
  }

  const int t = threadIdx.x;
  const int lane = t & 63;
  const int wv = t >> 6;                 // wave id: owns channels wv*32..+31
  const int row0 = blockIdx.x * 64;
  const int l15 = lane & 15, l4 = lane >> 4;

  // ---- W fragments -> registers as bf16 hi/lo ----
  bf16x8 Bh[2][4], Bl[2][4];
#pragma unroll
  for (int ct = 0; ct < 2; ++ct) {
    int ch = wv * 32 + ct * 16 + l15;
#pragma unroll
    for (int kf = 0; kf < 4; ++kf) {
      int k0 = kf * 32 + l4 * 8;
      const float* wp = W + (size_t)ch * 128 + k0;
      float4 w0 = *(const float4*)(wp);
      float4 w1 = *(const float4*)(wp + 4);
      float wf[8] = {w0.x, w0.y, w0.z, w0.w, w1.x, w1.y, w1.z, w1.w};
      bf16x8 hi, lo;
#pragma unroll
      for (int j = 0; j < 8; ++j) {
        ushort hb = f2bf(wf[j]);
        hi[j] = (short)hb;
        lo[j] = (short)f2bf(wf[j] - bf2f(hb));
      }
      Bh[ct][kf] = hi;
      Bl[ct][kf] = lo;
    }
  }

  // ---- stage x tile (64 rows) -> LDS bf16 hi/lo, 16B-chunk XOR swizzle ----
#pragma unroll
  for (int i = 0; i < 8; ++i) {
    int f4 = i * 256 + t;                // 2048 float4s
    int r = f4 >> 5;
    int k = (f4 & 31) * 4;
    int gr = row0 + r;
    float4 v = make_float4(0.f, 0.f, 0.f, 0.f);
    if (gr < N) v = ((const float4*)x)[(size_t)gr * 32 + (f4 & 31)];
    float vf[4] = {v.x, v.y, v.z, v.w};
    ushort hs[4], ls[4];
#pragma unroll
    for (int j = 0; j < 4; ++j) {
      hs[j] = f2bf(vf[j]);
      ls[j] = f2bf(vf[j] - bf2f(hs[j]));
    }
    int idx = r * 128 + (k ^ ((r & 7) << 3));
    uint2 hv, lv;
    hv.x = hs[0] | ((unsigned)hs[1] << 16);
    hv.y = hs[2] | ((unsigned)hs[3] << 16);
    lv.x = ls[0] | ((unsigned)ls[1] << 16);
    lv.y = ls[2] | ((unsigned)ls[3] << 16);
    *(uint2*)&xh[idx] = hv;
    *(uint2*)&xl[idx] = lv;
  }
  __syncthreads();

  // ---- MFMA: 4 row-tiles x 2 ch-tiles x 4 k-frags x 3 products ----
  f32x4 acc[4][2];
#pragma unroll
  for (int rt = 0; rt < 4; ++rt)
#pragma unroll
    for (int ct = 0; ct < 2; ++ct) acc[rt][ct] = (f32x4){0.f, 0.f, 0.f, 0.f};

#pragma unroll
  for (int kf = 0; kf < 4; ++kf) {
#pragma unroll
    for (int rt = 0; rt < 4; ++rt) {
      int r = rt * 16 + l15;
      int k = kf * 32 + l4 * 8;
      int idx = r * 128 + (k ^ ((r & 7) << 3));
      bf16x8 ah = *(const bf16x8*)&xh[idx];
      bf16x8 al = *(const bf16x8*)&xl[idx];
#pragma unroll
      for (int ct = 0; ct < 2; ++ct) {
        acc[rt][ct] = __builtin_amdgcn_mfma_f32_16x16x32_bf16(ah, Bh[ct][kf], acc[rt][ct], 0, 0, 0);
        acc[rt][ct] = __builtin_amdgcn_mfma_f32_16x16x32_bf16(al, Bh[ct][kf], acc[rt][ct], 0, 0, 0);
        acc[rt][ct] = __builtin_amdgcn_mfma_f32_16x16x32_bf16(ah, Bl[ct][kf], acc[rt][ct], 0, 0, 0);
      }
    }
  }

  // ---- store Zh head-major; D layout: col=lane&15, row=(lane>>4)*4+j ----
  float bv[2];
  bv[0] = bias[wv * 32 + l15];
  bv[1] = bias[wv * 32 + 16 + l15];
#pragma unroll
  for (int rt = 0; rt < 4; ++rt) {
#pragma unroll
    for (int ct = 0; ct < 2; ++ct) {
      int ch = wv * 32 + ct * 16 + l15;       // ch = o*4+h (ref channel)
      unsigned zc = (unsigned)((ch & 3) * 32 + (ch >> 2));  // head-major
#pragma unroll
      for (int j = 0; j < 4; ++j) {
        int r = row0 + rt * 16 + l4 * 4 + j;
        if (r < N) {
          float v = acc[rt][ct][j] + bv[ct];
          Zh[(unsigned)r * 128 + zc] = f2bf(v);
        }
      }
    }
  }
}

// ---- fused: node_e blocks [0, G1) | scan1 blocks [G1, G1+NB) ----
__global__ __launch_bounds__(256) void node_scan(
    const ushort* __restrict__ Zh, const float* __restrict__ a_l,
    const float* __restrict__ a_r, float* __restrict__ el,
    float* __restrict__ er, int N4,
    const int* __restrict__ deg, int* __restrict__ basev,
    int* __restrict__ bsum, int N, int G1) {
  __shared__ float sal[128], sar[128];
  __shared__ int ss[256];
  int t = threadIdx.x;

  if ((int)blockIdx.x < G1) {
    // ---- node_e: el/er[n,h] = sum_o Zh[n,h,o] * a[o*4+h] ----
    if (t < 128) { sal[t] = a_l[t]; sar[t] = a_r[t]; }
    __syncthreads();
    int idx = blockIdx.x * 256 + t;       // n*4 + h
    if (idx >= N4) return;
    int n = idx >> 2, h = idx & 3;
    const ushort* zp = Zh + (unsigned)n * 128 + h * 32;
    float sl = 0.f, sr = 0.f;
#pragma unroll
    for (int q = 0; q < 8; ++q) {
      uint2 zz = *(const uint2*)&zp[q * 4];
      float z0 = bf2f((ushort)(zz.x & 0xffff));
      float z1 = bf2f((ushort)(zz.x >> 16));
      float z2 = bf2f((ushort)(zz.y & 0xffff));
      float z3 = bf2f((ushort)(zz.y >> 16));
      int o = q * 4;
      sl += z0 * sal[(o + 0) * 4 + h] + z1 * sal[(o + 1) * 4 + h]
          + z2 * sal[(o + 2) * 4 + h] + z3 * sal[(o + 3) * 4 + h];
      sr += z0 * sar[(o + 0) * 4 + h] + z1 * sar[(o + 1) * 4 + h]
          + z2 * sar[(o + 2) * 4 + h] + z3 * sar[(o + 3) * 4 + h];
    }
    el[idx] = sl;
    er[idx] = sr;
  } else {
    // ---- scan1: per-256-block exclusive prefix of deg ----
    int bid = (int)blockIdx.x - G1;
    int i = bid * 256 + t;
    int v = (i < N) ? deg[i] : 0;
    ss[t] = v;
    __syncthreads();
#pragma unroll
    for (int off = 1; off < 256; off <<= 1) {
      int u = (t >= off) ? ss[t - off] : 0;
      __syncthreads();
      ss[t] += u;
      __syncthreads();
    }
    if (i < N) basev[i] = ss[t] - v;
    if (t == 255) bsum[bid] = ss[255];
  }
}

__global__ __launch_bounds__(512) void scan2(int* __restrict__ bsum, int NB) {
  __shared__ int s[512];
  int v = (threadIdx.x < NB) ? bsum[threadIdx.x] : 0;
  s[threadIdx.x] = v;
  __syncthreads();
#pragma unroll
  for (int off = 1; off < 512; off <<= 1) {
    int t = (threadIdx.x >= off) ? s[threadIdx.x - off] : 0;
    __syncthreads();
    s[threadIdx.x] += t;
    __syncthreads();
  }
  if (threadIdx.x < NB) bsum[threadIdx.x] = s[threadIdx.x] - v;
}

__global__ __launch_bounds__(256) void fill(
    const int* __restrict__ row, const int* __restrict__ col,
    const int* __restrict__ rank, const int* __restrict__ base,
    const int* __restrict__ bsum, int* __restrict__ sorted_col, int E) {
  int e = blockIdx.x * 256 + threadIdx.x;
  if (e < E) {
    int r = row[e];
    sorted_col[base[r] + bsum[r >> 8] + rank[e]] = col[e];
  }
}

__global__ __launch_bounds__(256) void gather(
    const int* __restrict__ base, const int* __restrict__ bsum,
    const int* __restrict__ deg, const int* __restrict__ sorted_col,
    const float* __restrict__ el, const float* __restrict__ er,
    const ushort* __restrict__ Zh, float* __restrict__ out, int N) {
  int t = threadIdx.x;
  int lane = t & 63;
  int n = blockIdx.x * 4 + (t >> 6);
  if (n >= N) return;
  int h = lane >> 4;                  // head
  int j = lane & 15;                  // edge sub-index within 16-chunk
  int s = base[n] + bsum[n >> 8];
  int d = deg[n];
  int end = s + d;
  float elv = el[((unsigned)n << 2) + h];
  float acc0 = 0.f, acc1 = 0.f, sumA = 0.f;
  const unsigned* Zh32 = (const unsigned*)Zh;
  const unsigned zlane = (unsigned)lane;
  const int bpb = (lane & 48) << 2;   // bpermute byte base = (h*16)*4

  for (int p = s; p < end; p += 16) {
    int cnt = end - p;
    if (cnt > 16) cnt = 16;
    // phase A: one exp per (edge, head), done by lane h*16+j for edge p+j
    int cl = 0;
    float xv = 0.f;
    if (j < cnt) {
      cl = sorted_col[p + j];
      float e = elv + er[((unsigned)cl << 2) + h];
      e = fmaxf(e, 0.2f * e);          // LeakyReLU(0.2)
      xv = __expf(e);
    }
    sumA += xv;
    // phase B: broadcast (xv, cl) in-register, accumulate 2 channels/lane
    for (int jj = 0; jj < cnt; ++jj) {
      int a = bpb + (jj << 2);
      float xvb = __builtin_bit_cast(float,
          __builtin_amdgcn_ds_bpermute(a, __builtin_bit_cast(int, xv)));
      unsigned clb = (unsigned)__builtin_amdgcn_ds_bpermute(a, cl);
      unsigned zz = Zh32[(clb << 6) + zlane];
      acc0 = fmaf(xvb, __builtin_bit_cast(float, zz << 16), acc0);
      acc1 = fmaf(xvb, __builtin_bit_cast(float, zz & 0xffff0000u), acc1);
    }
  }
  // reduce denom over the 16 lanes of this head group
  float sum = sumA;
  sum += __shfl_xor(sum, 1, 64);
  sum += __shfl_xor(sum, 2, 64);
  sum += __shfl_xor(sum, 4, 64);
  sum += __shfl_xor(sum, 8, 64);
  float inv = (d > 0) ? 1.0f / sum : 0.f;
  unsigned o0 = (unsigned)(j << 1);
  unsigned ob = ((unsigned)n << 7) + (o0 << 2) + (unsigned)h;  // o*4+h layout
  out[ob] = acc0 * inv;
  out[ob + 4] = acc1 * inv;
}

extern "C" void kernel_launch(void* const* d_in, const int* in_sizes, int n_in,
                              void* d_out, int out_size, void* d_ws, size_t ws_size,
                              hipStream_t stream) {
  const float* x   = (const float*)d_in[0];
  const int*   row = (const int*)d_in[1];
  const int*   col = (const int*)d_in[2];
  const float* W   = (const float*)d_in[3];
  const float* b   = (const float*)d_in[4];
  const float* a_l = (const float*)d_in[5];
  const float* a_r = (const float*)d_in[6];
  float* out = (float*)d_out;

  const int N = in_sizes[0] / 128;
  const int E = in_sizes[1];
  const int NB = (N + 255) / 256;

  char* w = (char*)d_ws;
  ushort* Zh       = (ushort*)w;             w += (size_t)N * 128 * 2;
  int*   sorted_col= (int*)w;                w += (size_t)E * 4;
  int*   rank      = (int*)w;                w += (size_t)E * 4;
  float* el        = (float*)w;              w += (size_t)N * 4 * 4;
  float* er        = (float*)w;              w += (size_t)N * 4 * 4;
  int*   deg       = (int*)w;                w += (size_t)N * 4;
  int*   base      = (int*)w;                w += (size_t)N * 4;
  int*   bsum      = (int*)w;                w += 512 * 4;

  hipMemsetAsync(deg, 0, (size_t)N * sizeof(int), stream);

  const int G1g = (N + 63) / 64;             // gemm blocks
  const int G2d = (E + 255) / 256;           // deg blocks
  gemm_deg<<<G1g + G2d, 256, 0, stream>>>(x, W, b, Zh, N, row, deg, rank, E, G1g);

  const int G1n = (N * 4 + 255) / 256;       // node_e blocks
  node_scan<<<G1n + NB, 256, 0, stream>>>(Zh, a_l, a_r, el, er, N * 4,
                                          deg, base, bsum, N, G1n);
  scan2<<<1, 512, 0, stream>>>(bsum, NB);
  fill<<<(E + 255) / 256, 256, 0, stream>>>(row, col, rank, base, bsum,
                                            sorted_col, E);
  gather<<<(N + 3) / 4, 256, 0, stream>>>(base, bsum, deg, sorted_col, el, er,
                                          Zh, out, N);
}

// Round 7
// 208.943 us; speedup vs baseline: 1.2284x; 1.2284x over previous
//
#include <hip/hip_runtime.h>
#include <hip/hip_bf16.h>
#include <math.h>

// ---------------------------------------------------------------------------
// GATConv forward.  N=100000, E=1.6M, IN=128, OUT*HEADS=128 (OUT=32, H=4).
// Round 7:
//   - gemm_deg: grid-fused {MFMA bf16x3 gemm (head-major bf16 Z)} || {deg_cnt}.
//   - node_scan: grid-fused {node_e} || {scan1}.  scan2 -> fill.
//   - gather: two-phase, BRANCH-FREE UNROLLED phase B.  Phase A: 64 lanes =
//     16 edges x 4 heads, one exp per (edge,head).  Phase B: 32 batched
//     ds_bpermute (xv, cl<<6), 16 batched Zh dword loads (latency overlap),
//     32 fma.  Invalid lanes carry xv=0/cl=0 -> fma adds 0, loads broadcast.
// ---------------------------------------------------------------------------

typedef __attribute__((ext_vector_type(8))) short bf16x8;
typedef __attribute__((ext_vector_type(4))) float f32x4;

__device__ __forceinline__ ushort f2bf(float f) {
  __hip_bfloat16 h = __float2bfloat16(f);   // RNE
  return __builtin_bit_cast(ushort, h);
}
__device__ __forceinline__ float bf2f(ushort u) {
  unsigned v = ((unsigned)u) << 16;
  return __builtin_bit_cast(float, v);
}

// ---- fused: gemm blocks [0, G1) | deg_cnt blocks [G1, G1+G2) ----
__global__ __launch_bounds__(256, 2) void gemm_deg(
    const float* __restrict__ x, const float* __restrict__ W,
    const float* __restrict__ bias, ushort* __restrict__ Zh, int N,
    const int* __restrict__ row, int* __restrict__ deg,
    int* __restrict__ rank, int E, int G1) {
  __shared__ ushort xh[64 * 128];
  __shared__ ushort xl[64 * 128];

  if ((int)blockIdx.x >= G1) {
    int e = ((int)blockIdx.x - G1) * 256 + threadIdx.x;
    if (e < E) rank[e] = atomicAdd(&deg[row[e]], 1);
    return;
  }

  const int t = threadIdx.x;
  const int lane = t & 63;
  const int wv = t >> 6;                 // wave id: owns channels wv*32..+31
  const int row0 = blockIdx.x * 64;
  const int l15 = lane & 15, l4 = lane >> 4;

  // ---- W fragments -> registers as bf16 hi/lo ----
  bf16x8 Bh[2][4], Bl[2][4];
#pragma unroll
  for (int ct = 0; ct < 2; ++ct) {
    int ch = wv * 32 + ct * 16 + l15;
#pragma unroll
    for (int kf = 0; kf < 4; ++kf) {
      int k0 = kf * 32 + l4 * 8;
      const float* wp = W + (size_t)ch * 128 + k0;
      float4 w0 = *(const float4*)(wp);
      float4 w1 = *(const float4*)(wp + 4);
      float wf[8] = {w0.x, w0.y, w0.z, w0.w, w1.x, w1.y, w1.z, w1.w};
      bf16x8 hi, lo;
#pragma unroll
      for (int j = 0; j < 8; ++j) {
        ushort hb = f2bf(wf[j]);
        hi[j] = (short)hb;
        lo[j] = (short)f2bf(wf[j] - bf2f(hb));
      }
      Bh[ct][kf] = hi;
      Bl[ct][kf] = lo;
    }
  }

  // ---- stage x tile (64 rows) -> LDS bf16 hi/lo, 16B-chunk XOR swizzle ----
#pragma unroll
  for (int i = 0; i < 8; ++i) {
    int f4 = i * 256 + t;                // 2048 float4s
    int r = f4 >> 5;
    int k = (f4 & 31) * 4;
    int gr = row0 + r;
    float4 v = make_float4(0.f, 0.f, 0.f, 0.f);
    if (gr < N) v = ((const float4*)x)[(size_t)gr * 32 + (f4 & 31)];
    float vf[4] = {v.x, v.y, v.z, v.w};
    ushort hs[4], ls[4];
#pragma unroll
    for (int j = 0; j < 4; ++j) {
      hs[j] = f2bf(vf[j]);
      ls[j] = f2bf(vf[j] - bf2f(hs[j]));
    }
    int idx = r * 128 + (k ^ ((r & 7) << 3));
    uint2 hv, lv;
    hv.x = hs[0] | ((unsigned)hs[1] << 16);
    hv.y = hs[2] | ((unsigned)hs[3] << 16);
    lv.x = ls[0] | ((unsigned)ls[1] << 16);
    lv.y = ls[2] | ((unsigned)ls[3] << 16);
    *(uint2*)&xh[idx] = hv;
    *(uint2*)&xl[idx] = lv;
  }
  __syncthreads();

  // ---- MFMA: 4 row-tiles x 2 ch-tiles x 4 k-frags x 3 products ----
  f32x4 acc[4][2];
#pragma unroll
  for (int rt = 0; rt < 4; ++rt)
#pragma unroll
    for (int ct = 0; ct < 2; ++ct) acc[rt][ct] = (f32x4){0.f, 0.f, 0.f, 0.f};

#pragma unroll
  for (int kf = 0; kf < 4; ++kf) {
#pragma unroll
    for (int rt = 0; rt < 4; ++rt) {
      int r = rt * 16 + l15;
      int k = kf * 32 + l4 * 8;
      int idx = r * 128 + (k ^ ((r & 7) << 3));
      bf16x8 ah = *(const bf16x8*)&xh[idx];
      bf16x8 al = *(const bf16x8*)&xl[idx];
#pragma unroll
      for (int ct = 0; ct < 2; ++ct) {
        acc[rt][ct] = __builtin_amdgcn_mfma_f32_16x16x32_bf16(ah, Bh[ct][kf], acc[rt][ct], 0, 0, 0);
        acc[rt][ct] = __builtin_amdgcn_mfma_f32_16x16x32_bf16(al, Bh[ct][kf], acc[rt][ct], 0, 0, 0);
        acc[rt][ct] = __builtin_amdgcn_mfma_f32_16x16x32_bf16(ah, Bl[ct][kf], acc[rt][ct], 0, 0, 0);
      }
    }
  }

  // ---- store Zh head-major; D layout: col=lane&15, row=(lane>>4)*4+j ----
  float bv[2];
  bv[0] = bias[wv * 32 + l15];
  bv[1] = bias[wv * 32 + 16 + l15];
#pragma unroll
  for (int rt = 0; rt < 4; ++rt) {
#pragma unroll
    for (int ct = 0; ct < 2; ++ct) {
      int ch = wv * 32 + ct * 16 + l15;       // ch = o*4+h (ref channel)
      unsigned zc = (unsigned)((ch & 3) * 32 + (ch >> 2));  // head-major
#pragma unroll
      for (int j = 0; j < 4; ++j) {
        int r = row0 + rt * 16 + l4 * 4 + j;
        if (r < N) {
          float v = acc[rt][ct][j] + bv[ct];
          Zh[(unsigned)r * 128 + zc] = f2bf(v);
        }
      }
    }
  }
}

// ---- fused: node_e blocks [0, G1) | scan1 blocks [G1, G1+NB) ----
__global__ __launch_bounds__(256) void node_scan(
    const ushort* __restrict__ Zh, const float* __restrict__ a_l,
    const float* __restrict__ a_r, float* __restrict__ el,
    float* __restrict__ er, int N4,
    const int* __restrict__ deg, int* __restrict__ basev,
    int* __restrict__ bsum, int N, int G1) {
  __shared__ float sal[128], sar[128];
  __shared__ int ss[256];
  int t = threadIdx.x;

  if ((int)blockIdx.x < G1) {
    // ---- node_e: el/er[n,h] = sum_o Zh[n,h,o] * a[o*4+h] ----
    if (t < 128) { sal[t] = a_l[t]; sar[t] = a_r[t]; }
    __syncthreads();
    int idx = blockIdx.x * 256 + t;       // n*4 + h
    if (idx >= N4) return;
    int n = idx >> 2, h = idx & 3;
    const ushort* zp = Zh + (unsigned)n * 128 + h * 32;
    float sl = 0.f, sr = 0.f;
#pragma unroll
    for (int q = 0; q < 8; ++q) {
      uint2 zz = *(const uint2*)&zp[q * 4];
      float z0 = bf2f((ushort)(zz.x & 0xffff));
      float z1 = bf2f((ushort)(zz.x >> 16));
      float z2 = bf2f((ushort)(zz.y & 0xffff));
      float z3 = bf2f((ushort)(zz.y >> 16));
      int o = q * 4;
      sl += z0 * sal[(o + 0) * 4 + h] + z1 * sal[(o + 1) * 4 + h]
          + z2 * sal[(o + 2) * 4 + h] + z3 * sal[(o + 3) * 4 + h];
      sr += z0 * sar[(o + 0) * 4 + h] + z1 * sar[(o + 1) * 4 + h]
          + z2 * sar[(o + 2) * 4 + h] + z3 * sar[(o + 3) * 4 + h];
    }
    el[idx] = sl;
    er[idx] = sr;
  } else {
    // ---- scan1: per-256-block exclusive prefix of deg ----
    int bid = (int)blockIdx.x - G1;
    int i = bid * 256 + t;
    int v = (i < N) ? deg[i] : 0;
    ss[t] = v;
    __syncthreads();
#pragma unroll
    for (int off = 1; off < 256; off <<= 1) {
      int u = (t >= off) ? ss[t - off] : 0;
      __syncthreads();
      ss[t] += u;
      __syncthreads();
    }
    if (i < N) basev[i] = ss[t] - v;
    if (t == 255) bsum[bid] = ss[255];
  }
}

__global__ __launch_bounds__(512) void scan2(int* __restrict__ bsum, int NB) {
  __shared__ int s[512];
  int v = (threadIdx.x < NB) ? bsum[threadIdx.x] : 0;
  s[threadIdx.x] = v;
  __syncthreads();
#pragma unroll
  for (int off = 1; off < 512; off <<= 1) {
    int t = (threadIdx.x >= off) ? s[threadIdx.x - off] : 0;
    __syncthreads();
    s[threadIdx.x] += t;
    __syncthreads();
  }
  if (threadIdx.x < NB) bsum[threadIdx.x] = s[threadIdx.x] - v;
}

__global__ __launch_bounds__(256) void fill(
    const int* __restrict__ row, const int* __restrict__ col,
    const int* __restrict__ rank, const int* __restrict__ base,
    const int* __restrict__ bsum, int* __restrict__ sorted_col, int E) {
  int e = blockIdx.x * 256 + threadIdx.x;
  if (e < E) {
    int r = row[e];
    sorted_col[base[r] + bsum[r >> 8] + rank[e]] = col[e];
  }
}

__global__ __launch_bounds__(256) void gather(
    const int* __restrict__ base, const int* __restrict__ bsum,
    const int* __restrict__ deg, const int* __restrict__ sorted_col,
    const float* __restrict__ el, const float* __restrict__ er,
    const ushort* __restrict__ Zh, float* __restrict__ out, int N) {
  int t = threadIdx.x;
  int lane = t & 63;
  int n = blockIdx.x * 4 + (t >> 6);
  if (n >= N) return;
  int h = lane >> 4;                  // head
  int j = lane & 15;                  // edge sub-index within 16-chunk
  int s = base[n] + bsum[n >> 8];
  int d = deg[n];
  int end = s + d;
  float elv = el[((unsigned)n << 2) + h];
  float acc0 = 0.f, acc1 = 0.f, sumA = 0.f;
  const unsigned* Zh32 = (const unsigned*)Zh;
  const unsigned zlane = (unsigned)lane;
  const int bpb = (lane & 48) << 2;   // bpermute byte base = (h*16)*4

  for (int p = s; p < end; p += 16) {
    int cnt = end - p;                // lanes with j < cnt are valid
    // phase A: one exp per (edge, head); invalid lanes carry xv=0, cl6=0
    int cl6 = 0;
    float xv = 0.f;
    if (j < cnt) {
      int cl = sorted_col[p + j];
      float e = elv + er[((unsigned)cl << 2) + h];
      e = fmaxf(e, 0.2f * e);          // LeakyReLU(0.2)
      xv = __expf(e);
      cl6 = cl << 6;                   // dword offset of Zh row
    }
    sumA += xv;
    // phase B: batched broadcasts, batched loads, batched fma (branch-free)
    float xvb[16];
    unsigned addr[16];
#pragma unroll
    for (int jj = 0; jj < 16; ++jj) {
      int a = bpb + (jj << 2);
      xvb[jj] = __builtin_bit_cast(float,
          __builtin_amdgcn_ds_bpermute(a, __builtin_bit_cast(int, xv)));
      addr[jj] = (unsigned)__builtin_amdgcn_ds_bpermute(a, cl6) + zlane;
    }
    unsigned zz[16];
#pragma unroll
    for (int jj = 0; jj < 16; ++jj) zz[jj] = Zh32[addr[jj]];
#pragma unroll
    for (int jj = 0; jj < 16; ++jj) {
      acc0 = fmaf(xvb[jj], __builtin_bit_cast(float, zz[jj] << 16), acc0);
      acc1 = fmaf(xvb[jj], __builtin_bit_cast(float, zz[jj] & 0xffff0000u), acc1);
    }
  }
  // reduce denom over the 16 lanes of this head group
  float sum = sumA;
  sum += __shfl_xor(sum, 1, 64);
  sum += __shfl_xor(sum, 2, 64);
  sum += __shfl_xor(sum, 4, 64);
  sum += __shfl_xor(sum, 8, 64);
  float inv = (d > 0) ? 1.0f / sum : 0.f;
  unsigned o0 = (unsigned)(j << 1);
  unsigned ob = ((unsigned)n << 7) + (o0 << 2) + (unsigned)h;  // o*4+h layout
  out[ob] = acc0 * inv;
  out[ob + 4] = acc1 * inv;
}

extern "C" void kernel_launch(void* const* d_in, const int* in_sizes, int n_in,
                              void* d_out, int out_size, void* d_ws, size_t ws_size,
                              hipStream_t stream) {
  const float* x   = (const float*)d_in[0];
  const int*   row = (const int*)d_in[1];
  const int*   col = (const int*)d_in[2];
  const float* W   = (const float*)d_in[3];
  const float* b   = (const float*)d_in[4];
  const float* a_l = (const float*)d_in[5];
  const float* a_r = (const float*)d_in[6];
  float* out = (float*)d_out;

  const int N = in_sizes[0] / 128;
  const int E = in_sizes[1];
  const int NB = (N + 255) / 256;

  char* w = (char*)d_ws;
  ushort* Zh       = (ushort*)w;             w += (size_t)N * 128 * 2;
  int*   sorted_col= (int*)w;                w += (size_t)E * 4;
  int*   rank      = (int*)w;                w += (size_t)E * 4;
  float* el        = (float*)w;              w += (size_t)N * 4 * 4;
  float* er        = (float*)w;              w += (size_t)N * 4 * 4;
  int*   deg       = (int*)w;                w += (size_t)N * 4;
  int*   base      = (int*)w;                w += (size_t)N * 4;
  int*   bsum      = (int*)w;                w += 512 * 4;

  hipMemsetAsync(deg, 0, (size_t)N * sizeof(int), stream);

  const int G1g = (N + 63) / 64;             // gemm blocks
  const int G2d = (E + 255) / 256;           // deg blocks
  gemm_deg<<<G1g + G2d, 256, 0, stream>>>(x, W, b, Zh, N, row, deg, rank, E, G1g);

  const int G1n = (N * 4 + 255) / 256;       // node_e blocks
  node_scan<<<G1n + NB, 256, 0, stream>>>(Zh, a_l, a_r, el, er, N * 4,
                                          deg, base, bsum, N, G1n);
  scan2<<<1, 512, 0, stream>>>(bsum, NB);
  fill<<<(E + 255) / 256, 256, 0, stream>>>(row, col, rank, base, bsum,
                                            sorted_col, E);
  gather<<<(N + 3) / 4, 256, 0, stream>>>(base, bsum, deg, sorted_col, el, er,
                                          Zh, out, N);
}